// Round 2
// baseline (494.832 us; speedup 1.0000x reference)
//
#include <hip/hip_runtime.h>
#include <stdint.h>

typedef _Float16 half8 __attribute__((ext_vector_type(8)));
typedef float f32x16 __attribute__((ext_vector_type(16)));

#define NH 49

__device__ __forceinline__ uint32_t pk2(float a, float b){
  auto p = __builtin_amdgcn_cvt_pkrtz(a, b);   // __fp16 ext_vector_type(2)
  return __builtin_bit_cast(uint32_t, p);
}
__device__ __forceinline__ uint32_t pk2_relu(float a, float b){
  return pk2(__builtin_fmaxf(a, 0.f), __builtin_fmaxf(b, 0.f));
}

// exchange so that: a' = hi ? partner(b) : a ; b' = hi ? b : partner(a)
__device__ __forceinline__ void xswap(uint32_t& a, uint32_t& b, int hi){
  uint32_t ta = (uint32_t)__shfl_xor((int)a, 32, 64);
  uint32_t tb = (uint32_t)__shfl_xor((int)b, 32, 64);
  uint32_t na = hi ? tb : a;
  uint32_t nb = hi ? b  : ta;
  a = na; b = nb;
}

// Build one B-fragment (4 dwords = 8 fp16) for a 16-wide K-slice from 8 acc regs.
// acc C-layout: reg r (in [8*RH, 8*RH+8)) holds feature (r&3) + 8*(r>>2) + 4*hi (+32*mt).
// B-layout needs lane to hold k = 8*hi + e within this 16-wide K slice.
template<int RH>
__device__ __forceinline__ void build4(const f32x16& c, int hi, uint32_t* d){
  uint32_t p0 = pk2_relu(c[8*RH+0], c[8*RH+1]);
  uint32_t p1 = pk2_relu(c[8*RH+2], c[8*RH+3]);
  uint32_t p2 = pk2_relu(c[8*RH+4], c[8*RH+5]);
  uint32_t p3 = pk2_relu(c[8*RH+6], c[8*RH+7]);
  xswap(p0, p2, hi);
  xswap(p1, p3, hi);
  d[0]=p0; d[1]=p1; d[2]=p2; d[3]=p3;
}

__device__ __forceinline__ half8 toh8(const uint32_t* d){
  union { uint32_t u[4]; half8 h; } v;
  v.u[0]=d[0]; v.u[1]=d[1]; v.u[2]=d[2]; v.u[3]=d[3];
  return v.h;
}

// Load bias into MFMA C layout: c[4g+i] = sbase[32*mt + 8*g + 4*hi + i]
__device__ __forceinline__ f32x16 bias_c(const float* sbase, int mt, int hi){
  f32x16 c;
  #pragma unroll
  for (int g=0; g<4; ++g){
    const float* p = sbase + 32*mt + 8*g + 4*hi;
    c[4*g+0]=p[0]; c[4*g+1]=p[1]; c[4*g+2]=p[2]; c[4*g+3]=p[3];
  }
  return c;
}

// ---- prep: convert fp32 weights to fp16 A-fragments in ws ----
// frag group order: [w_in mt=0..1][hid (l,kt,mt) flat][w_out kt=0..3]
// A-frag layout (32x32x16): lane holds A[m = 32*mt + (lane&31)][k = 16*kt + 8*(lane>>5) + e]
__global__ void prep_weights(const float* __restrict__ w_in,
                             const float* __restrict__ w_hid,
                             const float* __restrict__ w_out,
                             half8* __restrict__ wf)
{
  int bid = blockIdx.x;
  int lane = threadIdx.x;
  int hi = lane >> 5, lo = lane & 31;
  half8 f;
  if (bid < 2){
    int mt = bid, row = 32*mt + lo;
    #pragma unroll
    for (int e=0; e<8; ++e){
      int k = 8*hi + e;
      f[e] = (k < 10) ? (_Float16)w_in[row*10 + k] : (_Float16)0.f;
    }
  } else if (bid < 394){
    int t = bid - 2;
    int l = t >> 3, kt = (t >> 1) & 3, mt = t & 1;
    int row = 32*mt + lo;
    #pragma unroll
    for (int e=0; e<8; ++e){
      int k = 16*kt + 8*hi + e;
      f[e] = (_Float16)w_hid[(l*64 + row)*64 + k];
    }
  } else {
    int kt = bid - 394;
    #pragma unroll
    for (int e=0; e<8; ++e){
      int k = 16*kt + 8*hi + e;
      f[e] = (lo < 10) ? (_Float16)w_out[lo*64 + k] : (_Float16)0.f;
    }
  }
  wf[bid*64 + lane] = f;
}

// ---- fused MLP: 1 wave owns 128 batch rows through all 51 layers ----
__global__ __launch_bounds__(256, 2) void mlp_fused(
    const float* __restrict__ x,
    const float* __restrict__ b_in,
    const float* __restrict__ b_hid,
    const float* __restrict__ b_out,
    const half8* __restrict__ wfrag,
    float* __restrict__ out)
{
  __shared__ __attribute__((aligned(16))) float sb[50*64 + 32];
  for (int i = threadIdx.x; i < 64; i += 256)     sb[i]      = b_in[i];
  for (int i = threadIdx.x; i < NH*64; i += 256)  sb[64 + i] = b_hid[i];
  if (threadIdx.x < 32) sb[3200 + threadIdx.x] = (threadIdx.x < 10) ? b_out[threadIdx.x] : 0.f;
  __syncthreads();

  const int lane = threadIdx.x & 63;
  const int wid  = threadIdx.x >> 6;
  const int hi   = lane >> 5;
  const int col  = lane & 31;
  const long rowbase = ((long)blockIdx.x * 4 + wid) * 128;

  f32x16 acc[4][2];       // [bt][mt] : 128 batch rows x 64 features, f32
  uint32_t bf[4][4][4];   // [bt][kt][dword] : fp16 B-fragments

  // ---- layer 0: x[*,10] (K padded to 16; kt=0 only) ----
  {
    half8 a0 = wfrag[lane];
    half8 a1 = wfrag[64 + lane];
    f32x16 cb0 = bias_c(sb, 0, hi);
    f32x16 cb1 = bias_c(sb, 1, hi);
    #pragma unroll
    for (int bt=0; bt<4; ++bt){
      const float* xr = x + (rowbase + bt*32 + col) * 10;
      float xv[8];
      if (hi == 0){
        #pragma unroll
        for (int j=0;j<8;++j) xv[j] = xr[j];
      } else {
        xv[0]=xr[8]; xv[1]=xr[9];
        #pragma unroll
        for (int j=2;j<8;++j) xv[j]=0.f;
      }
      uint32_t d[4] = { pk2(xv[0],xv[1]), pk2(xv[2],xv[3]),
                        pk2(xv[4],xv[5]), pk2(xv[6],xv[7]) };
      half8 bx = toh8(d);
      acc[bt][0] = __builtin_amdgcn_mfma_f32_32x32x16_f16(a0, bx, cb0, 0,0,0);
      acc[bt][1] = __builtin_amdgcn_mfma_f32_32x32x16_f16(a1, bx, cb1, 0,0,0);
    }
  }

  // ---- 49 hidden layers ----
  const half8* wf = wfrag + 128;
  #pragma unroll 1
  for (int l = 0; l < NH; ++l){
    #pragma unroll
    for (int bt=0; bt<4; ++bt){
      build4<0>(acc[bt][0], hi, bf[bt][0]);   // k  0..15
      build4<1>(acc[bt][0], hi, bf[bt][1]);   // k 16..31
      build4<0>(acc[bt][1], hi, bf[bt][2]);   // k 32..47
      build4<1>(acc[bt][1], hi, bf[bt][3]);   // k 48..63
    }
    const float* sbl = sb + 64 + 64*l;
    f32x16 cb0 = bias_c(sbl, 0, hi);
    f32x16 cb1 = bias_c(sbl, 1, hi);
    #pragma unroll
    for (int kt=0; kt<4; ++kt){
      half8 a0 = wf[((l*4 + kt)*2 + 0)*64 + lane];
      half8 a1 = wf[((l*4 + kt)*2 + 1)*64 + lane];
      #pragma unroll
      for (int bt=0; bt<4; ++bt){
        half8 bb = toh8(bf[bt][kt]);
        if (kt == 0){
          acc[bt][0] = __builtin_amdgcn_mfma_f32_32x32x16_f16(a0, bb, cb0, 0,0,0);
          acc[bt][1] = __builtin_amdgcn_mfma_f32_32x32x16_f16(a1, bb, cb1, 0,0,0);
        } else {
          acc[bt][0] = __builtin_amdgcn_mfma_f32_32x32x16_f16(a0, bb, acc[bt][0], 0,0,0);
          acc[bt][1] = __builtin_amdgcn_mfma_f32_32x32x16_f16(a1, bb, acc[bt][1], 0,0,0);
        }
      }
    }
  }

  // ---- output layer: 64 -> 10 ----
  #pragma unroll
  for (int bt=0; bt<4; ++bt){
    build4<0>(acc[bt][0], hi, bf[bt][0]);
    build4<1>(acc[bt][0], hi, bf[bt][1]);
    build4<0>(acc[bt][1], hi, bf[bt][2]);
    build4<1>(acc[bt][1], hi, bf[bt][3]);
  }
  const half8* wo = wfrag + 128 + 392*64;
  f32x16 cbo = bias_c(sb + 3200, 0, hi);
  f32x16 oacc[4];
  #pragma unroll
  for (int kt=0; kt<4; ++kt){
    half8 aw = wo[kt*64 + lane];
    #pragma unroll
    for (int bt=0; bt<4; ++bt){
      half8 bb = toh8(bf[bt][kt]);
      oacc[bt] = (kt==0) ? __builtin_amdgcn_mfma_f32_32x32x16_f16(aw, bb, cbo, 0,0,0)
                         : __builtin_amdgcn_mfma_f32_32x32x16_f16(aw, bb, oacc[bt], 0,0,0);
    }
  }
  // D rows -> output features: hi==0: regs {0,1,2,3}->o{0..3}, regs {4,5}->o{8,9}
  //                            hi==1: regs {0,1,2,3}->o{4..7}
  #pragma unroll
  for (int bt=0; bt<4; ++bt){
    float* orow = out + (rowbase + bt*32 + col) * 10;
    if (hi == 0){
      *(float2*)(orow + 0) = make_float2(oacc[bt][0], oacc[bt][1]);
      *(float2*)(orow + 2) = make_float2(oacc[bt][2], oacc[bt][3]);
      *(float2*)(orow + 8) = make_float2(oacc[bt][4], oacc[bt][5]);
    } else {
      *(float2*)(orow + 4) = make_float2(oacc[bt][0], oacc[bt][1]);
      *(float2*)(orow + 6) = make_float2(oacc[bt][2], oacc[bt][3]);
    }
  }
}

extern "C" void kernel_launch(void* const* d_in, const int* in_sizes, int n_in,
                              void* d_out, int out_size, void* d_ws, size_t ws_size,
                              hipStream_t stream)
{
  const float* x     = (const float*)d_in[0];
  const float* w_in  = (const float*)d_in[1];
  const float* b_in  = (const float*)d_in[2];
  const float* w_hid = (const float*)d_in[3];
  const float* b_hid = (const float*)d_in[4];
  const float* w_out = (const float*)d_in[5];
  const float* b_out = (const float*)d_in[6];
  half8* wf = (half8*)d_ws;   // needs 407,552 bytes

  prep_weights<<<398, 64, 0, stream>>>(w_in, w_hid, w_out, wf);
  mlp_fused<<<2048, 256, 0, stream>>>(x, b_in, b_hid, b_out, wf, (float*)d_out);
}

// Round 3
// 474.670 us; speedup vs baseline: 1.0425x; 1.0425x over previous
//
#include <hip/hip_runtime.h>
#include <stdint.h>

typedef _Float16 half8 __attribute__((ext_vector_type(8)));
typedef float f32x16 __attribute__((ext_vector_type(16)));
typedef float f32x4  __attribute__((ext_vector_type(4)));

#define NH 49

__device__ __forceinline__ uint32_t pk2(float a, float b){
  auto p = __builtin_amdgcn_cvt_pkrtz(a, b);   // __fp16 ext_vector_type(2)
  return __builtin_bit_cast(uint32_t, p);
}
__device__ __forceinline__ uint32_t relu2(uint32_t p){
  uint32_t r, z = 0u;
  asm("v_pk_max_f16 %0, %1, %2" : "=v"(r) : "v"(p), "v"(z));
  return r;
}

// Convert 8 consecutive acc regs (C-layout) to one B-fragment K-half, with ReLU.
// With the phi(bit2<->bit3) weight pre-permutation, this is PURE in-lane:
// B frag kt <- acc[kt>>1] regs [8*(kt&1) .. 8*(kt&1)+7], packed pairwise.
template<int RH>
__device__ __forceinline__ void cvt4(const f32x16& c, uint32_t* d){
  d[0] = relu2(pk2(c[8*RH+0], c[8*RH+1]));
  d[1] = relu2(pk2(c[8*RH+2], c[8*RH+3]));
  d[2] = relu2(pk2(c[8*RH+4], c[8*RH+5]));
  d[3] = relu2(pk2(c[8*RH+6], c[8*RH+7]));
}

__device__ __forceinline__ half8 toh8(const uint32_t* d){
  union { uint32_t u[4]; half8 h; } v;
  v.u[0]=d[0]; v.u[1]=d[1]; v.u[2]=d[2]; v.u[3]=d[3];
  return v.h;
}

// Bias into MFMA C layout: c[4g+i] = sbase[32*mt + 8*g + 4*hi + i]  (16B-aligned LDS reads)
__device__ __forceinline__ f32x16 bias_c(const float* sbase, int mt, int hi){
  f32x16 c;
  const float* b = sbase + 32*mt + 4*hi;
  #pragma unroll
  for (int g=0; g<4; ++g){
    f32x4 v = *(const f32x4*)(b + 8*g);
    c[4*g+0]=v[0]; c[4*g+1]=v[1]; c[4*g+2]=v[2]; c[4*g+3]=v[3];
  }
  return c;
}

// phi: swap bits 2 and 3 of a 6-bit feature index (involution)
__device__ __forceinline__ int phi(int k){
  return (k & 51) | ((k & 4) << 1) | ((k & 8) >> 1);
}

// ---- prep: fp32 weights -> fp16 A-fragments in ws ----
// frag order: [w_in mt=0..1][hid (l,kt,mt) flat][w_out kt=0..3]
// A-frag (32x32x16): lane holds A[m=32mt+(lane&31)][k=16kt+8*(lane>>5)+e]
// Hidden + out fragments store column phi(k) so the activation relayout is in-lane.
__global__ void prep_weights(const float* __restrict__ w_in,
                             const float* __restrict__ w_hid,
                             const float* __restrict__ w_out,
                             half8* __restrict__ wf)
{
  int bid = blockIdx.x;
  int lane = threadIdx.x;
  int hi = lane >> 5, lo = lane & 31;
  half8 f;
  if (bid < 2){
    int mt = bid, row = 32*mt + lo;
    #pragma unroll
    for (int e=0; e<8; ++e){
      int k = 8*hi + e;
      f[e] = (k < 10) ? (_Float16)w_in[row*10 + k] : (_Float16)0.f;
    }
  } else if (bid < 394){
    int t = bid - 2;
    int l = t >> 3, kt = (t >> 1) & 3, mt = t & 1;
    int row = 32*mt + lo;
    #pragma unroll
    for (int e=0; e<8; ++e){
      int k = 16*kt + 8*hi + e;
      f[e] = (_Float16)w_hid[(l*64 + row)*64 + phi(k)];
    }
  } else {
    int kt = bid - 394;
    #pragma unroll
    for (int e=0; e<8; ++e){
      int k = 16*kt + 8*hi + e;
      f[e] = (lo < 10) ? (_Float16)w_out[lo*64 + phi(k)] : (_Float16)0.f;
    }
  }
  wf[bid*64 + lane] = f;
}

// stage one hidden layer's 8 fragments (8 KB) into LDS; wave wid moves frags 2wid, 2wid+1
__device__ __forceinline__ void stage_layer(const half8* gsrc, half8* ldst, int wid, int lane){
  const void* g0 = (const void*)(gsrc + (2*wid    )*64 + lane);
  const void* g1 = (const void*)(gsrc + (2*wid + 1)*64 + lane);
  void* l0 = (void*)(ldst + (2*wid    )*64);
  void* l1 = (void*)(ldst + (2*wid + 1)*64);
  __builtin_amdgcn_global_load_lds((const __attribute__((address_space(1))) void*)g0,
                                   (__attribute__((address_space(3))) void*)l0, 16, 0, 0);
  __builtin_amdgcn_global_load_lds((const __attribute__((address_space(1))) void*)g1,
                                   (__attribute__((address_space(3))) void*)l1, 16, 0, 0);
}

__device__ __forceinline__ f32x16 mfma16(half8 a, half8 b, f32x16 c){
  return __builtin_amdgcn_mfma_f32_32x32x16_f16(a, b, c, 0, 0, 0);
}

// one hidden layer: read weights from LDS buf, barrier, prefetch h+2 into same buf,
// relayout + MFMA, counted-vmcnt drain of h+1's stage, barrier.
__device__ __forceinline__ void hlayer(int h, const half8* rb, half8* wbdst,
    const half8* whid, const float* sbh, int wid, int lane, int hi,
    f32x16 (&acc)[4][2])
{
  half8 w[8];
  #pragma unroll
  for (int f=0; f<8; ++f) w[f] = rb[f*64 + lane];
  const float* bl = sbh + (h << 6);
  f32x16 cb0 = bias_c(bl, 0, hi);
  f32x16 cb1 = bias_c(bl, 1, hi);
  asm volatile("s_waitcnt lgkmcnt(0)" ::: "memory");
  __builtin_amdgcn_s_barrier();                 // all waves done reading rb
  bool stg = (h + 2 < NH);
  if (stg) stage_layer(whid + (h + 2)*512, wbdst, wid, lane);

  #pragma unroll
  for (int bt=0; bt<4; ++bt){
    uint32_t bfr[16];
    cvt4<0>(acc[bt][0], bfr + 0);
    cvt4<1>(acc[bt][0], bfr + 4);
    cvt4<0>(acc[bt][1], bfr + 8);
    cvt4<1>(acc[bt][1], bfr + 12);
    half8 b0 = toh8(bfr+0), b1 = toh8(bfr+4), b2 = toh8(bfr+8), b3 = toh8(bfr+12);
    acc[bt][0] = mfma16(w[0], b0, cb0);        acc[bt][1] = mfma16(w[1], b0, cb1);
    acc[bt][0] = mfma16(w[2], b1, acc[bt][0]); acc[bt][1] = mfma16(w[3], b1, acc[bt][1]);
    acc[bt][0] = mfma16(w[4], b2, acc[bt][0]); acc[bt][1] = mfma16(w[5], b2, acc[bt][1]);
    acc[bt][0] = mfma16(w[6], b3, acc[bt][0]); acc[bt][1] = mfma16(w[7], b3, acc[bt][1]);
  }

  if (stg) asm volatile("s_waitcnt vmcnt(2)" ::: "memory");  // h+1's stage complete
  else     asm volatile("s_waitcnt vmcnt(0)" ::: "memory");
  __builtin_amdgcn_s_barrier();
}

// ---- fused MLP: 1 wave owns 128 batch rows through all 51 layers ----
__global__ __launch_bounds__(256, 2) void mlp_fused(
    const float* __restrict__ x,
    const float* __restrict__ b_in,
    const float* __restrict__ b_hid,
    const float* __restrict__ b_out,
    const half8* __restrict__ wfrag,
    float* __restrict__ out)
{
  __shared__ __attribute__((aligned(16))) float sb[50*64 + 32];
  __shared__ __attribute__((aligned(16))) half8 wlds[2][512];

  for (int i = threadIdx.x; i < 64; i += 256)     sb[i]      = b_in[i];
  for (int i = threadIdx.x; i < NH*64; i += 256)  sb[64 + i] = b_hid[i];
  if (threadIdx.x < 32) sb[3200 + threadIdx.x] = (threadIdx.x < 10) ? b_out[threadIdx.x] : 0.f;
  __syncthreads();

  const int lane = threadIdx.x & 63;
  const int wid  = threadIdx.x >> 6;
  const int hi   = lane >> 5;
  const int col  = lane & 31;
  const long rowbase = ((long)blockIdx.x * 4 + wid) * 128;
  const half8* whid = wfrag + 128;
  const float* sbh  = sb + 64;

  // prefetch hidden layers 0 and 1 while layer 0 computes
  stage_layer(whid,       &wlds[0][0], wid, lane);
  stage_layer(whid + 512, &wlds[1][0], wid, lane);

  f32x16 acc[4][2];   // [bt][mt]: 128 batch rows x 64 features

  // ---- input layer: x[*,10] (K padded to 16) ----
  {
    half8 a0 = wfrag[lane];
    half8 a1 = wfrag[64 + lane];
    f32x16 cb0 = bias_c(sb, 0, hi);
    f32x16 cb1 = bias_c(sb, 1, hi);
    #pragma unroll
    for (int bt=0; bt<4; ++bt){
      const float* xr = x + (rowbase + bt*32 + col) * 10;
      float xv[8];
      if (hi == 0){
        #pragma unroll
        for (int j=0;j<8;++j) xv[j] = xr[j];
      } else {
        xv[0]=xr[8]; xv[1]=xr[9];
        #pragma unroll
        for (int j=2;j<8;++j) xv[j]=0.f;
      }
      uint32_t d[4] = { pk2(xv[0],xv[1]), pk2(xv[2],xv[3]),
                        pk2(xv[4],xv[5]), pk2(xv[6],xv[7]) };
      half8 bx = toh8(d);
      acc[bt][0] = mfma16(a0, bx, cb0);
      acc[bt][1] = mfma16(a1, bx, cb1);
    }
  }

  asm volatile("s_waitcnt vmcnt(2)" ::: "memory");  // hidden layer 0 staged
  __builtin_amdgcn_s_barrier();

  // ---- 49 hidden layers, LDS double-buffered ----
  #pragma unroll 1
  for (int h = 0; h < NH-1; h += 2){
    hlayer(h,   &wlds[0][0], &wlds[0][0], whid, sbh, wid, lane, hi, acc);
    hlayer(h+1, &wlds[1][0], &wlds[1][0], whid, sbh, wid, lane, hi, acc);
  }
  hlayer(NH-1, &wlds[0][0], &wlds[0][0], whid, sbh, wid, lane, hi, acc);

  // ---- output layer: 64 -> 10 ----
  const half8* wo = wfrag + 128 + 392*64;
  f32x16 cbo = bias_c(sb + 3200, 0, hi);
  f32x16 oacc[4];
  #pragma unroll
  for (int bt=0; bt<4; ++bt){
    uint32_t bfr[16];
    cvt4<0>(acc[bt][0], bfr + 0);
    cvt4<1>(acc[bt][0], bfr + 4);
    cvt4<0>(acc[bt][1], bfr + 8);
    cvt4<1>(acc[bt][1], bfr + 12);
    #pragma unroll
    for (int kt=0; kt<4; ++kt){
      half8 aw = wo[kt*64 + lane];
      half8 bb = toh8(bfr + 4*kt);
      oacc[bt] = (kt==0) ? mfma16(aw, bb, cbo) : mfma16(aw, bb, oacc[bt]);
    }
  }
  // D rows -> out features: hi==0: regs{0..3}->o0..3, regs{4,5}->o8,9 ; hi==1: regs{0..3}->o4..7
  #pragma unroll
  for (int bt=0; bt<4; ++bt){
    float* orow = out + (rowbase + bt*32 + col) * 10;
    if (hi == 0){
      *(float2*)(orow + 0) = make_float2(oacc[bt][0], oacc[bt][1]);
      *(float2*)(orow + 2) = make_float2(oacc[bt][2], oacc[bt][3]);
      *(float2*)(orow + 8) = make_float2(oacc[bt][4], oacc[bt][5]);
    } else {
      *(float2*)(orow + 4) = make_float2(oacc[bt][0], oacc[bt][1]);
      *(float2*)(orow + 6) = make_float2(oacc[bt][2], oacc[bt][3]);
    }
  }
}

extern "C" void kernel_launch(void* const* d_in, const int* in_sizes, int n_in,
                              void* d_out, int out_size, void* d_ws, size_t ws_size,
                              hipStream_t stream)
{
  const float* x     = (const float*)d_in[0];
  const float* w_in  = (const float*)d_in[1];
  const float* b_in  = (const float*)d_in[2];
  const float* w_hid = (const float*)d_in[3];
  const float* b_hid = (const float*)d_in[4];
  const float* w_out = (const float*)d_in[5];
  const float* b_out = (const float*)d_in[6];
  half8* wf = (half8*)d_ws;   // 398 KiB of A-fragments

  prep_weights<<<398, 64, 0, stream>>>(w_in, w_hid, w_out, wf);
  mlp_fused<<<2048, 256, 0, stream>>>(x, b_in, b_hid, b_out, wf, (float*)d_out);
}

// Round 4
// 317.763 us; speedup vs baseline: 1.5572x; 1.4938x over previous
//
#include <hip/hip_runtime.h>
#include <stdint.h>

typedef _Float16 half8 __attribute__((ext_vector_type(8)));
typedef float f32x16 __attribute__((ext_vector_type(16)));
typedef float f32x4  __attribute__((ext_vector_type(4)));

#define NH 49

__device__ __forceinline__ uint32_t pk2(float a, float b){
  auto p = __builtin_amdgcn_cvt_pkrtz(a, b);
  return __builtin_bit_cast(uint32_t, p);
}
__device__ __forceinline__ uint32_t relu2(uint32_t p){
  uint32_t r, z = 0u;
  asm("v_pk_max_f16 %0, %1, %2" : "=v"(r) : "v"(p), "v"(z));
  return r;
}

// acc C-layout regs -> packed fp16 pairs with ReLU (pure in-lane thanks to the
// phi(bit2<->bit3) weight pre-permutation).
template<int RH>
__device__ __forceinline__ void cvt4(const f32x16& c, uint32_t* d){
  d[0] = relu2(pk2(c[8*RH+0], c[8*RH+1]));
  d[1] = relu2(pk2(c[8*RH+2], c[8*RH+3]));
  d[2] = relu2(pk2(c[8*RH+4], c[8*RH+5]));
  d[3] = relu2(pk2(c[8*RH+6], c[8*RH+7]));
}

__device__ __forceinline__ half8 toh8(const uint32_t* d){
  union { uint32_t u[4]; half8 h; } v;
  v.u[0]=d[0]; v.u[1]=d[1]; v.u[2]=d[2]; v.u[3]=d[3];
  return v.h;
}

// Bias into MFMA C layout: c[4g+i] = sbase[32*mt + 8*g + 4*hi + i]
__device__ __forceinline__ f32x16 bias_c(const float* sbase, int mt, int hi){
  f32x16 c;
  const float* b = sbase + 32*mt + 4*hi;
  #pragma unroll
  for (int g=0; g<4; ++g){
    f32x4 v = *(const f32x4*)(b + 8*g);
    c[4*g+0]=v[0]; c[4*g+1]=v[1]; c[4*g+2]=v[2]; c[4*g+3]=v[3];
  }
  return c;
}

// phi: swap bits 2 and 3 of a 6-bit feature index (involution)
__device__ __forceinline__ int phi(int k){
  return (k & 51) | ((k & 4) << 1) | ((k & 8) >> 1);
}

// ---- prep: fp32 weights -> fp16 A-fragments (phi-permuted K columns) ----
__global__ void prep_weights(const float* __restrict__ w_in,
                             const float* __restrict__ w_hid,
                             const float* __restrict__ w_out,
                             half8* __restrict__ wf)
{
  int bid = blockIdx.x;
  int lane = threadIdx.x;
  int hi = lane >> 5, lo = lane & 31;
  half8 f;
  if (bid < 2){
    int mt = bid, row = 32*mt + lo;
    #pragma unroll
    for (int e=0; e<8; ++e){
      int k = 8*hi + e;
      f[e] = (k < 10) ? (_Float16)w_in[row*10 + k] : (_Float16)0.f;
    }
  } else if (bid < 394){
    int t = bid - 2;
    int l = t >> 3, kt = (t >> 1) & 3, mt = t & 1;
    int row = 32*mt + lo;
    #pragma unroll
    for (int e=0; e<8; ++e){
      int k = 16*kt + 8*hi + e;
      f[e] = (_Float16)w_hid[(l*64 + row)*64 + phi(k)];
    }
  } else {
    int kt = bid - 394;
    #pragma unroll
    for (int e=0; e<8; ++e){
      int k = 16*kt + 8*hi + e;
      f[e] = (lo < 10) ? (_Float16)w_out[lo*64 + phi(k)] : (_Float16)0.f;
    }
  }
  wf[bid*64 + lane] = f;
}

// stage one layer's 8 fragments (8 KB) into LDS; wave wid moves frags 2wid, 2wid+1
__device__ __forceinline__ void stage_layer(const half8* gsrc, half8* ldst, int wid, int lane){
  const void* g0 = (const void*)(gsrc + (2*wid    )*64 + lane);
  const void* g1 = (const void*)(gsrc + (2*wid + 1)*64 + lane);
  void* l0 = (void*)(ldst + (2*wid    )*64);
  void* l1 = (void*)(ldst + (2*wid + 1)*64);
  __builtin_amdgcn_global_load_lds((const __attribute__((address_space(1))) void*)g0,
                                   (__attribute__((address_space(3))) void*)l0, 16, 0, 0);
  __builtin_amdgcn_global_load_lds((const __attribute__((address_space(1))) void*)g1,
                                   (__attribute__((address_space(3))) void*)l1, 16, 0, 0);
}

__device__ __forceinline__ f32x16 mfma16(half8 a, half8 b, f32x16 c){
  return __builtin_amdgcn_mfma_f32_32x32x16_f16(a, b, c, 0, 0, 0);
}

// One hidden layer. rb = this layer's LDS weight buffer (already complete).
// Issues stage of layer h+2 into sdst immediately (post previous barrier),
// computes, then counted-vmcnt drain + single barrier.
__device__ __forceinline__ void hlayer(const half8* rb,
    const half8* ssrc, half8* sdst, bool st,
    const float* bl, int wid, int lane, int hi,
    f32x16 (&acc)[4][2])
{
  if (st) stage_layer(ssrc, sdst, wid, lane);
  f32x16 cb0 = bias_c(bl, 0, hi);
  f32x16 cb1 = bias_c(bl, 1, hi);

  #pragma unroll
  for (int half=0; half<2; ++half){
    uint32_t bfr[2][16];
    #pragma unroll
    for (int j=0; j<2; ++j){
      int bt = 2*half + j;
      cvt4<0>(acc[bt][0], bfr[j]+0);
      cvt4<1>(acc[bt][0], bfr[j]+4);
      cvt4<0>(acc[bt][1], bfr[j]+8);
      cvt4<1>(acc[bt][1], bfr[j]+12);
    }
    __builtin_amdgcn_s_setprio(1);
    #pragma unroll
    for (int kt=0; kt<4; ++kt){
      half8 w0 = rb[(2*kt    )*64 + lane];
      half8 w1 = rb[(2*kt + 1)*64 + lane];
      #pragma unroll
      for (int j=0; j<2; ++j){
        int bt = 2*half + j;
        half8 bb = toh8(bfr[j] + 4*kt);
        acc[bt][0] = mfma16(w0, bb, kt ? acc[bt][0] : cb0);
        acc[bt][1] = mfma16(w1, bb, kt ? acc[bt][1] : cb1);
      }
    }
    __builtin_amdgcn_s_setprio(0);
  }

  if (st) asm volatile("s_waitcnt vmcnt(2)" ::: "memory"); // next layer staged
  else    asm volatile("s_waitcnt vmcnt(0)" ::: "memory");
  __builtin_amdgcn_s_barrier();
}

// ---- fused MLP: 1 wave owns 128 batch rows through all 51 layers ----
__global__ __launch_bounds__(256, 2) void mlp_fused(
    const float* __restrict__ x,
    const float* __restrict__ b_in,
    const float* __restrict__ b_hid,
    const float* __restrict__ b_out,
    const half8* __restrict__ wfrag,
    float* __restrict__ out)
{
  __shared__ __attribute__((aligned(16))) float sb[50*64 + 32];
  __shared__ __attribute__((aligned(16))) half8 wlds[3][512];

  for (int i = threadIdx.x; i < 64; i += 256)     sb[i]      = b_in[i];
  for (int i = threadIdx.x; i < NH*64; i += 256)  sb[64 + i] = b_hid[i];
  if (threadIdx.x < 32) sb[3200 + threadIdx.x] = (threadIdx.x < 10) ? b_out[threadIdx.x] : 0.f;
  __syncthreads();

  const int lane = threadIdx.x & 63;
  const int wid  = threadIdx.x >> 6;
  const int hi   = lane >> 5;
  const int col  = lane & 31;
  const long rowbase = ((long)blockIdx.x * 4 + wid) * 128;
  const half8* whid = wfrag + 128;
  const float* sbh  = sb + 64;

  // prefetch hidden layers 0,1 while the input layer computes
  stage_layer(whid,       &wlds[0][0], wid, lane);
  stage_layer(whid + 512, &wlds[1][0], wid, lane);

  f32x16 acc[4][2];   // [bt][mt]: 128 batch rows x 64 features

  // ---- input layer: x[*,10] (K padded to 16) ----
  {
    half8 a0 = wfrag[lane];
    half8 a1 = wfrag[64 + lane];
    f32x16 cb0 = bias_c(sb, 0, hi);
    f32x16 cb1 = bias_c(sb, 1, hi);
    #pragma unroll
    for (int bt=0; bt<4; ++bt){
      const float* xr = x + (rowbase + bt*32 + col) * 10;
      float xv[8];
      if (hi == 0){
        #pragma unroll
        for (int j=0;j<8;++j) xv[j] = xr[j];
      } else {
        xv[0]=xr[8]; xv[1]=xr[9];
        #pragma unroll
        for (int j=2;j<8;++j) xv[j]=0.f;
      }
      uint32_t d[4] = { pk2(xv[0],xv[1]), pk2(xv[2],xv[3]),
                        pk2(xv[4],xv[5]), pk2(xv[6],xv[7]) };
      half8 bx = toh8(d);
      acc[bt][0] = mfma16(a0, bx, cb0);
      acc[bt][1] = mfma16(a1, bx, cb1);
    }
  }

  asm volatile("s_waitcnt vmcnt(2)" ::: "memory");  // layer 0 weights staged
  __builtin_amdgcn_s_barrier();

  // ---- 49 hidden layers, triple-buffered, one barrier per layer ----
  #pragma unroll 1
  for (int h = 0; h < NH-1; h += 3){
    hlayer(&wlds[0][0], whid + (h+2)*512, &wlds[2][0], (h+2)<NH, sbh + ((h  )<<6), wid, lane, hi, acc);
    hlayer(&wlds[1][0], whid + (h+3)*512, &wlds[0][0], (h+3)<NH, sbh + ((h+1)<<6), wid, lane, hi, acc);
    hlayer(&wlds[2][0], whid + (h+4)*512, &wlds[1][0], (h+4)<NH, sbh + ((h+2)<<6), wid, lane, hi, acc);
  }
  hlayer(&wlds[0][0], whid, &wlds[2][0], false, sbh + ((NH-1)<<6), wid, lane, hi, acc);

  // ---- output layer: 64 -> 10 ----
  const half8* wo = wfrag + 128 + 392*64;
  f32x16 cbo = bias_c(sb + 3200, 0, hi);
  f32x16 oacc[4];
  #pragma unroll
  for (int bt=0; bt<4; ++bt){
    uint32_t bfr[16];
    cvt4<0>(acc[bt][0], bfr + 0);
    cvt4<1>(acc[bt][0], bfr + 4);
    cvt4<0>(acc[bt][1], bfr + 8);
    cvt4<1>(acc[bt][1], bfr + 12);
    #pragma unroll
    for (int kt=0; kt<4; ++kt){
      half8 aw = wo[kt*64 + lane];
      half8 bb = toh8(bfr + 4*kt);
      oacc[bt] = (kt==0) ? mfma16(aw, bb, cbo) : mfma16(aw, bb, oacc[bt]);
    }
  }
  // D rows -> out features: hi==0: regs{0..3}->o0..3, regs{4,5}->o8,9 ; hi==1: regs{0..3}->o4..7
  #pragma unroll
  for (int bt=0; bt<4; ++bt){
    float* orow = out + (rowbase + bt*32 + col) * 10;
    if (hi == 0){
      *(float2*)(orow + 0) = make_float2(oacc[bt][0], oacc[bt][1]);
      *(float2*)(orow + 2) = make_float2(oacc[bt][2], oacc[bt][3]);
      *(float2*)(orow + 8) = make_float2(oacc[bt][4], oacc[bt][5]);
    } else {
      *(float2*)(orow + 4) = make_float2(oacc[bt][0], oacc[bt][1]);
      *(float2*)(orow + 6) = make_float2(oacc[bt][2], oacc[bt][3]);
    }
  }
}

extern "C" void kernel_launch(void* const* d_in, const int* in_sizes, int n_in,
                              void* d_out, int out_size, void* d_ws, size_t ws_size,
                              hipStream_t stream)
{
  const float* x     = (const float*)d_in[0];
  const float* w_in  = (const float*)d_in[1];
  const float* b_in  = (const float*)d_in[2];
  const float* w_hid = (const float*)d_in[3];
  const float* b_hid = (const float*)d_in[4];
  const float* w_out = (const float*)d_in[5];
  const float* b_out = (const float*)d_in[6];
  half8* wf = (half8*)d_ws;   // 398 KiB of A-fragments

  prep_weights<<<398, 64, 0, stream>>>(w_in, w_hid, w_out, wf);
  mlp_fused<<<2048, 256, 0, stream>>>(x, b_in, b_hid, b_out, wf, (float*)d_out);
}

// Round 5
// 311.299 us; speedup vs baseline: 1.5896x; 1.0208x over previous
//
#include <hip/hip_runtime.h>
#include <stdint.h>

typedef _Float16 half8 __attribute__((ext_vector_type(8)));
typedef float f32x16 __attribute__((ext_vector_type(16)));
typedef float f32x4  __attribute__((ext_vector_type(4)));

#define NH 49

__device__ __forceinline__ uint32_t pk2(float a, float b){
  auto p = __builtin_amdgcn_cvt_pkrtz(a, b);
  return __builtin_bit_cast(uint32_t, p);
}
__device__ __forceinline__ uint32_t relu2(uint32_t p){
  uint32_t r, z = 0u;
  asm("v_pk_max_f16 %0, %1, %2" : "=v"(r) : "v"(p), "v"(z));
  return r;
}

// acc C-layout regs -> packed fp16 pairs with ReLU (pure in-lane thanks to the
// phi(bit2<->bit3) weight pre-permutation).
template<int RH>
__device__ __forceinline__ void cvt4(const f32x16& c, uint32_t* d){
  d[0] = relu2(pk2(c[8*RH+0], c[8*RH+1]));
  d[1] = relu2(pk2(c[8*RH+2], c[8*RH+3]));
  d[2] = relu2(pk2(c[8*RH+4], c[8*RH+5]));
  d[3] = relu2(pk2(c[8*RH+6], c[8*RH+7]));
}

__device__ __forceinline__ half8 toh8(const uint32_t* d){
  union { uint32_t u[4]; half8 h; } v;
  v.u[0]=d[0]; v.u[1]=d[1]; v.u[2]=d[2]; v.u[3]=d[3];
  return v.h;
}

// Bias into MFMA C layout: c[4g+i] = sbase[32*mt + 8*g + 4*hi + i]
__device__ __forceinline__ f32x16 bias_c(const float* sbase, int mt, int hi){
  f32x16 c;
  const float* b = sbase + 32*mt + 4*hi;
  #pragma unroll
  for (int g=0; g<4; ++g){
    f32x4 v = *(const f32x4*)(b + 8*g);
    c[4*g+0]=v[0]; c[4*g+1]=v[1]; c[4*g+2]=v[2]; c[4*g+3]=v[3];
  }
  return c;
}

// phi: swap bits 2 and 3 of a 6-bit feature index (involution)
__device__ __forceinline__ int phi(int k){
  return (k & 51) | ((k & 4) << 1) | ((k & 8) >> 1);
}

// ---- prep: fp32 weights -> fp16 A-fragments (phi-permuted K columns) ----
__global__ void prep_weights(const float* __restrict__ w_in,
                             const float* __restrict__ w_hid,
                             const float* __restrict__ w_out,
                             half8* __restrict__ wf)
{
  int bid = blockIdx.x;
  int lane = threadIdx.x;
  int hi = lane >> 5, lo = lane & 31;
  half8 f;
  if (bid < 2){
    int mt = bid, row = 32*mt + lo;
    #pragma unroll
    for (int e=0; e<8; ++e){
      int k = 8*hi + e;
      f[e] = (k < 10) ? (_Float16)w_in[row*10 + k] : (_Float16)0.f;
    }
  } else if (bid < 394){
    int t = bid - 2;
    int l = t >> 3, kt = (t >> 1) & 3, mt = t & 1;
    int row = 32*mt + lo;
    #pragma unroll
    for (int e=0; e<8; ++e){
      int k = 16*kt + 8*hi + e;
      f[e] = (_Float16)w_hid[(l*64 + row)*64 + phi(k)];
    }
  } else {
    int kt = bid - 394;
    #pragma unroll
    for (int e=0; e<8; ++e){
      int k = 16*kt + 8*hi + e;
      f[e] = (lo < 10) ? (_Float16)w_out[lo*64 + phi(k)] : (_Float16)0.f;
    }
  }
  wf[bid*64 + lane] = f;
}

__device__ __forceinline__ f32x16 mfma16(half8 a, half8 b, f32x16 c){
  return __builtin_amdgcn_mfma_f32_32x32x16_f16(a, b, c, 0, 0, 0);
}

// ---- fused MLP: 1 wave owns 128 batch rows through all 51 layers.
// No inter-wave synchronization in the layer loop: weights come straight from
// global (L1-resident broadcast), so the 2 waves/SIMD free-run and anti-phase,
// keeping the matrix pipe fed during each other's relayout gaps.
__global__ __launch_bounds__(256, 2) void mlp_fused(
    const float* __restrict__ x,
    const float* __restrict__ b_in,
    const float* __restrict__ b_hid,
    const float* __restrict__ b_out,
    const half8* __restrict__ wfrag,
    float* __restrict__ out)
{
  __shared__ __attribute__((aligned(16))) float sb[50*64 + 32];
  for (int i = threadIdx.x; i < 64; i += 256)     sb[i]      = b_in[i];
  for (int i = threadIdx.x; i < NH*64; i += 256)  sb[64 + i] = b_hid[i];
  if (threadIdx.x < 32) sb[3200 + threadIdx.x] = (threadIdx.x < 10) ? b_out[threadIdx.x] : 0.f;
  __syncthreads();   // only sync in the kernel

  const int lane = threadIdx.x & 63;
  const int wid  = threadIdx.x >> 6;
  const int hi   = lane >> 5;
  const int col  = lane & 31;
  const long rowbase = ((long)blockIdx.x * 4 + wid) * 128;
  const half8* whid = wfrag + 128;
  const float* sbh  = sb + 64;

  f32x16 acc[4][2];   // [bt][mt]: 128 batch rows x 64 features (AGPR)

  // ---- input layer: x[*,10] (K padded to 16) ----
  {
    half8 a0 = wfrag[lane];
    half8 a1 = wfrag[64 + lane];
    f32x16 cb0 = bias_c(sb, 0, hi);
    f32x16 cb1 = bias_c(sb, 1, hi);
    #pragma unroll
    for (int bt=0; bt<4; ++bt){
      const float* xr = x + (rowbase + bt*32 + col) * 10;
      float xv[8];
      if (hi == 0){
        #pragma unroll
        for (int j=0;j<8;++j) xv[j] = xr[j];
      } else {
        xv[0]=xr[8]; xv[1]=xr[9];
        #pragma unroll
        for (int j=2;j<8;++j) xv[j]=0.f;
      }
      uint32_t d[4] = { pk2(xv[0],xv[1]), pk2(xv[2],xv[3]),
                        pk2(xv[4],xv[5]), pk2(xv[6],xv[7]) };
      half8 bx = toh8(d);
      acc[bt][0] = mfma16(a0, bx, cb0);
      acc[bt][1] = mfma16(a1, bx, cb1);
    }
  }

  // ---- 49 hidden layers, barrier-free ----
  #pragma unroll 1
  for (int h = 0; h < NH; ++h){
    const half8* wl = whid + h*512;
    half8 w[8];
    #pragma unroll
    for (int f=0; f<8; ++f) w[f] = wl[f*64 + lane];   // global, L1-broadcast
    const float* bl = sbh + (h << 6);
    f32x16 cb0 = bias_c(bl, 0, hi);
    f32x16 cb1 = bias_c(bl, 1, hi);

    #pragma unroll
    for (int bt=0; bt<4; ++bt){
      uint32_t bfr[16];
      cvt4<0>(acc[bt][0], bfr + 0);
      cvt4<1>(acc[bt][0], bfr + 4);
      cvt4<0>(acc[bt][1], bfr + 8);
      cvt4<1>(acc[bt][1], bfr + 12);
      __builtin_amdgcn_s_setprio(1);
      #pragma unroll
      for (int kt=0; kt<4; ++kt){
        half8 bb = toh8(bfr + 4*kt);
        acc[bt][0] = mfma16(w[2*kt    ], bb, kt ? acc[bt][0] : cb0);
        acc[bt][1] = mfma16(w[2*kt + 1], bb, kt ? acc[bt][1] : cb1);
      }
      __builtin_amdgcn_s_setprio(0);
    }
  }

  // ---- output layer: 64 -> 10 ----
  const half8* wo = wfrag + 128 + 392*64;
  f32x16 cbo = bias_c(sb + 3200, 0, hi);
  f32x16 oacc[4];
  #pragma unroll
  for (int bt=0; bt<4; ++bt){
    uint32_t bfr[16];
    cvt4<0>(acc[bt][0], bfr + 0);
    cvt4<1>(acc[bt][0], bfr + 4);
    cvt4<0>(acc[bt][1], bfr + 8);
    cvt4<1>(acc[bt][1], bfr + 12);
    #pragma unroll
    for (int kt=0; kt<4; ++kt){
      half8 aw = wo[kt*64 + lane];
      half8 bb = toh8(bfr + 4*kt);
      oacc[bt] = (kt==0) ? mfma16(aw, bb, cbo) : mfma16(aw, bb, oacc[bt]);
    }
  }
  // D rows -> out features: hi==0: regs{0..3}->o0..3, regs{4,5}->o8,9 ; hi==1: regs{0..3}->o4..7
  #pragma unroll
  for (int bt=0; bt<4; ++bt){
    float* orow = out + (rowbase + bt*32 + col) * 10;
    if (hi == 0){
      *(float2*)(orow + 0) = make_float2(oacc[bt][0], oacc[bt][1]);
      *(float2*)(orow + 2) = make_float2(oacc[bt][2], oacc[bt][3]);
      *(float2*)(orow + 8) = make_float2(oacc[bt][4], oacc[bt][5]);
    } else {
      *(float2*)(orow + 4) = make_float2(oacc[bt][0], oacc[bt][1]);
      *(float2*)(orow + 6) = make_float2(oacc[bt][2], oacc[bt][3]);
    }
  }
}

extern "C" void kernel_launch(void* const* d_in, const int* in_sizes, int n_in,
                              void* d_out, int out_size, void* d_ws, size_t ws_size,
                              hipStream_t stream)
{
  const float* x     = (const float*)d_in[0];
  const float* w_in  = (const float*)d_in[1];
  const float* b_in  = (const float*)d_in[2];
  const float* w_hid = (const float*)d_in[3];
  const float* b_hid = (const float*)d_in[4];
  const float* w_out = (const float*)d_in[5];
  const float* b_out = (const float*)d_in[6];
  half8* wf = (half8*)d_ws;   // 398 KiB of A-fragments

  prep_weights<<<398, 64, 0, stream>>>(w_in, w_hid, w_out, wf);
  mlp_fused<<<2048, 256, 0, stream>>>(x, b_in, b_hid, b_out, wf, (float*)d_out);
}